// Round 11
// baseline (649.145 us; speedup 1.0000x reference)
//
#include <hip/hip_runtime.h>

#define NK 512
#define ND 64
#define NHW 4096
#define NPIX 131072            // 32*64*64
#define OUT_ELEMS 8388608      // 32*64*64*64
#define XS 68                  // LDS x-row stride (floats)

// ---------------------------------------------------------------------------
// Prep (2 blocks x 256): per code k
//   - sc[k] = numpy-pairwise-8 fp32 sum of fl(c_d^2)
//   - cbT4[dq*512 + k] = float4(cb[k][4dq..4dq+3])   (blocked transpose: the
//     main kernel's per-lane code loads become 256B-contiguous dwordx4)
//   - zero the two loss slots (harness re-poisons d_out/d_ws to 0xAA).
// d_ws layout: [cbT4: 8192 float4 = 128KB][sc: 512 floats].
// ---------------------------------------------------------------------------
__global__ __launch_bounds__(256) void vq_prep(const float* __restrict__ cb,
                                               float4* __restrict__ cbT4,
                                               float* __restrict__ sc,
                                               float* __restrict__ losses) {
#pragma clang fp contract(off)
  {
    int k = blockIdx.x * 256 + threadIdx.x;   // 0..511
    const float4* c4 = (const float4*)(cb + (size_t)k * ND);
    float4 row[16];
#pragma unroll
    for (int dq = 0; dq < 16; ++dq) row[dq] = c4[dq];
    // transpose: slab dq holds all codes' dq-quads contiguously by k
#pragma unroll
    for (int dq = 0; dq < 16; ++dq) cbT4[dq * NK + k] = row[dq];
    // sc: rounded squares then pairwise-8 (bitwise = numpy)
    float q[ND];
#pragma unroll
    for (int dq = 0; dq < 16; ++dq) {
      q[dq * 4 + 0] = row[dq].x * row[dq].x;
      q[dq * 4 + 1] = row[dq].y * row[dq].y;
      q[dq * 4 + 2] = row[dq].z * row[dq].z;
      q[dq * 4 + 3] = row[dq].w * row[dq].w;
    }
    float r[8];
#pragma unroll
    for (int j = 0; j < 8; ++j) r[j] = q[j];
#pragma unroll
    for (int i = 8; i < ND; i += 8)
#pragma unroll
      for (int j = 0; j < 8; ++j) r[j] += q[i + j];
    sc[k] = ((r[0] + r[1]) + (r[2] + r[3])) + ((r[4] + r[5]) + (r[6] + r[7]));
    if (k < 2) losses[k] = 0.f;
  }
}

// ---------------------------------------------------------------------------
// Main: 64 px/block, 256 threads. Lane (r=lane&3, c=lane>>2): m=4 pixels
// {wv*16 + i*4 + r} x n=8 codes {pass*128 + j*16 + c}. Per dq-step:
//   4 LDS b128 x-reads (1.5 LDS-cyc/quad, under the 2.0 budget) +
//   8 VMEM dwordx4 cb-loads from the blocked transpose (16 contiguous lanes
//   = 256B, L2-hot, in-order vmcnt; 1.5 VMEM-cyc/quad) + 32 quad-FMAs.
// R10 fed BOTH operands from the one per-CU LDS pipe (51k cyc/block vs the
// 16.4k VALU wall -> 3x over, measured 177us). K-loop has NO barriers: x is
// staged per-wave (self-contained), Sx via same-wave in-order DS, sc read
// from global. One barrier total (before the cross-wave epilogue).
// Numerics bit-identical to passing R2/R5/R7/R10: per-(n,k) sequential fp32
// FMA chain d=0..63 (dq ascending); d2 = fl(fl(Sx - fl(2M)) + Sc); Sx numpy
// pairwise-8; within-lane passes/j ascend + strict '<'; cross-lane
// lexicographic (val,idx) => lowest index wins ties = np.argmin.
// ---------------------------------------------------------------------------
__global__ __launch_bounds__(256, 2) void vq_main(const float* __restrict__ x,
                                                  const float* __restrict__ cb,
                                                  const float4* __restrict__ cbT4,
                                                  const float* __restrict__ sc,
                                                  float* __restrict__ out,
                                                  float* __restrict__ idx_out,
                                                  float* __restrict__ losses) {
#pragma clang fp contract(off)
  {
    __shared__ float lx[64 * XS];     // 17.4 KB x tile [pixel][d]
    __shared__ float sxb[64];         // per-pixel Sx
    __shared__ int   shw[64];         // winning code per pixel
    __shared__ float red[4];

    const int tid = threadIdx.x;
    const int wv = __builtin_amdgcn_readfirstlane(tid >> 6);  // wave id
    const int lane = tid & 63;
    const int r = lane & 3;           // pixel row
    const int c = lane >> 2;          // code col (0..15)
    const int g0 = blockIdx.x * 64;
    const int b = g0 >> 12;
    const int hw0 = g0 & 4095;
    const float* xbase = x + (size_t)b * (ND * NHW) + hw0;

    // ---- Per-wave x staging: wave wv stages its own 16 pixels, all dims.
    // lane = (p16 = lane&15, dg = lane>>4): pixel wv*16+p16, dims dg*16..+15.
    {
      const int p16 = lane & 15, dg = lane >> 4;
      const int px = wv * 16 + p16;
#pragma unroll
      for (int j = 0; j < 16; ++j) {
        const int d = dg * 16 + j;
        lx[px * XS + d] = xbase[(size_t)d * NHW + px];   // 64B segments
      }
    }
    // ---- Sx for this wave's pixels (lanes 0..15); same-wave DS ops are
    // in-order, so no barrier is needed before this wave reads sxb.
    if (lane < 16) {
      const int px = wv * 16 + lane;
      float rr[8];
      float4 q0 = *(const float4*)&lx[px * XS + 0];
      float4 q1 = *(const float4*)&lx[px * XS + 4];
      rr[0] = q0.x * q0.x; rr[1] = q0.y * q0.y; rr[2] = q0.z * q0.z; rr[3] = q0.w * q0.w;
      rr[4] = q1.x * q1.x; rr[5] = q1.y * q1.y; rr[6] = q1.z * q1.z; rr[7] = q1.w * q1.w;
#pragma unroll
      for (int i = 2; i < 16; i += 2) {
        float4 a = *(const float4*)&lx[px * XS + i * 4];
        float4 e = *(const float4*)&lx[px * XS + i * 4 + 4];
        rr[0] += a.x * a.x; rr[1] += a.y * a.y; rr[2] += a.z * a.z; rr[3] += a.w * a.w;
        rr[4] += e.x * e.x; rr[5] += e.y * e.y; rr[6] += e.z * e.z; rr[7] += e.w * e.w;
      }
      sxb[px] = ((rr[0] + rr[1]) + (rr[2] + rr[3])) + ((rr[4] + rr[5]) + (rr[6] + rr[7]));
    }
    const int px0 = wv * 16 + r;      // this lane's pixels: px0 + {0,4,8,12}
    float Sxi[4];
#pragma unroll
    for (int i = 0; i < 4; ++i) Sxi[i] = sxb[px0 + i * 4];

    // ---- K-loop: 4 passes x 128 codes, no barriers, no LDS cb traffic.
    float m1[4] = {3.0e38f, 3.0e38f, 3.0e38f, 3.0e38f};
    int   i1[4] = {0, 0, 0, 0};

    for (int pass = 0; pass < 4; ++pass) {
      const int kbase = pass * 128;
      float acc[4][8];
#pragma unroll
      for (int i = 0; i < 4; ++i)
#pragma unroll
        for (int j = 0; j < 8; ++j) acc[i][j] = 0.f;

#pragma unroll
      for (int dq = 0; dq < 16; ++dq) {
        // cb quads: slab dq, codes kbase + j*16 + c. 16 c-lanes contiguous
        // float4s (256B) x4 r-replication -> coalesced dwordx4, offset j*256.
        const float4* slab = cbT4 + ((dq * NK) + kbase + c);
        float4 cq[8];
#pragma unroll
        for (int j = 0; j < 8; ++j) cq[j] = slab[j * 16];
        float4 xq[4];
#pragma unroll
        for (int i = 0; i < 4; ++i)
          xq[i] = *(const float4*)&lx[(px0 + i * 4) * XS + dq * 4];
#pragma unroll
        for (int i = 0; i < 4; ++i)
#pragma unroll
          for (int j = 0; j < 8; ++j) {
            acc[i][j] = __builtin_fmaf(cq[j].x, xq[i].x, acc[i][j]);  // d=4dq
            acc[i][j] = __builtin_fmaf(cq[j].y, xq[i].y, acc[i][j]);  // sequential
            acc[i][j] = __builtin_fmaf(cq[j].z, xq[i].z, acc[i][j]);  // chain
            acc[i][j] = __builtin_fmaf(cq[j].w, xq[i].w, acc[i][j]);
          }
      }
      // Combine + running argmin (j ascends, then later passes: code order).
#pragma unroll
      for (int j = 0; j < 8; ++j) {
        const int code = kbase + j * 16 + c;
        const float scj = sc[code];          // global, 64B-coalesced, L2-hot
#pragma unroll
        for (int i = 0; i < 4; ++i) {
          const float d2 = (Sxi[i] - 2.0f * acc[i][j]) + scj;
          if (d2 < m1[i]) { m1[i] = d2; i1[i] = code; }
        }
      }
    }

    // ---- Cross-lane argmin per pixel over the 16 c-cols (lane bits 2..5);
    // lexicographic (val, idx) => exact np.argmin tie-breaking.
#pragma unroll
    for (int i = 0; i < 4; ++i) {
      float m = m1[i];
      int ii = i1[i];
#pragma unroll
      for (int s = 4; s < 64; s <<= 1) {
        const float om = __shfl_xor(m, s, 64);
        const int oi = __shfl_xor(ii, s, 64);
        if (om < m || (om == m && oi < ii)) { m = om; ii = oi; }
      }
      if (c == 0) {
        const int px = px0 + i * 4;
        shw[px] = ii;
        idx_out[g0 + px] = (float)ii;
      }
    }
    __syncthreads();   // shw + full x tile visible for the cross-wave epilogue

    // ---- Epilogue: wave wv writes dims [wv*16,+16) for all 64 pixels.
    const int p = lane;
    const int widx = shw[p];
    const float* qrow = cb + (size_t)widx * ND;
    float* op = out + (size_t)b * (ND * NHW) + hw0;
    float lossp = 0.f;
#pragma unroll
    for (int j = 0; j < 4; ++j) {
      const int d = wv * 16 + j * 4;
      const float4 q = *(const float4*)(qrow + d);
      const float4 xq = *(const float4*)&lx[p * XS + d];
      float e;
      e = xq.x - q.x; lossp = __builtin_fmaf(e, e, lossp); op[(size_t)(d + 0) * NHW + p] = q.x;
      e = xq.y - q.y; lossp = __builtin_fmaf(e, e, lossp); op[(size_t)(d + 1) * NHW + p] = q.y;
      e = xq.z - q.z; lossp = __builtin_fmaf(e, e, lossp); op[(size_t)(d + 2) * NHW + p] = q.z;
      e = xq.w - q.w; lossp = __builtin_fmaf(e, e, lossp); op[(size_t)(d + 3) * NHW + p] = q.w;
    }
#pragma unroll
    for (int off = 32; off; off >>= 1) lossp += __shfl_down(lossp, off);
    if (lane == 0) red[wv] = lossp;
    __syncthreads();
    if (tid == 0) {
      float t = (red[0] + red[1] + red[2] + red[3]) * (1.f / 8388608.f);
      atomicAdd(losses + 0, t);   // dictionary_loss
      atomicAdd(losses + 1, t);   // commitment_loss (identical forward value)
    }
  }
}

extern "C" void kernel_launch(void* const* d_in, const int* in_sizes, int n_in,
                              void* d_out, int out_size, void* d_ws, size_t ws_size,
                              hipStream_t stream) {
  const float* x  = (const float*)d_in[0];   // [32,64,64,64] fp32
  const float* cb = (const float*)d_in[1];   // [512,64] fp32
  float* out     = (float*)d_out;            // quantized [B,D,H,W]
  float* idx_out = out + OUT_ELEMS;          // indices (as fp32) [B,H,W]
  float* losses  = idx_out + NPIX;           // 2 scalars
  float4* cbT4   = (float4*)d_ws;            // 128 KB blocked transpose
  float*  sc     = (float*)d_ws + 4 * 8192;  // 512 floats after cbT4

  vq_prep<<<2, 256, 0, stream>>>(cb, cbT4, sc, losses);
  vq_main<<<NPIX / 64, 256, 0, stream>>>(x, cb, cbT4, sc, out, idx_out, losses);
}